// Round 7
// baseline (275.144 us; speedup 1.0000x reference)
//
#include <hip/hip_runtime.h>
#include <cstdint>
#include <cstddef>

// ---------------------------------------------------------------------------
// FlashSparseAttention on MI355X (gfx950)
// R7: XOR-swizzled LDS everywhere (conflict-free MFMA fragment reads while
//     keeping global_load_lds in GEMMs); attn split-KV x2 with additive
//     fp32 partials (fixed-max softmax) + combine kernel; Wo cvt folded.
// ---------------------------------------------------------------------------

typedef __bf16 bf16_t;
typedef bf16_t bf16x4_t __attribute__((ext_vector_type(4)));
typedef bf16_t bf16x8_t __attribute__((ext_vector_type(8)));
typedef float f32x4_t __attribute__((ext_vector_type(4)));

__device__ __forceinline__ void async_copy16(void* lds_base, const void* gsrc) {
  auto g = reinterpret_cast<__attribute__((address_space(1))) void*>(
      reinterpret_cast<uintptr_t>(gsrc));
  auto l = reinterpret_cast<__attribute__((address_space(3))) void*>(
      static_cast<uint32_t>(reinterpret_cast<uintptr_t>(lds_base)));
  __builtin_amdgcn_global_load_lds(g, l, 16, 0, 0);
}

// ---------------------------------------------------------------------------
// fp32 -> bf16: merged conversion of hidden/Wq/Wk/Wv/Wo (one launch)
// ---------------------------------------------------------------------------
__global__ __launch_bounds__(256) void cvt_all(const float* __restrict__ hs,
                                               const float* __restrict__ wq,
                                               const float* __restrict__ wk,
                                               const float* __restrict__ wv,
                                               const float* __restrict__ wo,
                                               bf16_t* __restrict__ regA,
                                               bf16_t* __restrict__ regB,
                                               bf16_t* __restrict__ regWo) {
  const int b = blockIdx.x;
  const float* src;
  bf16_t* dst;
  int rel;
  if (b < 4096) { src = hs; dst = regA; rel = b; }
  else if (b < 8192) { src = wq; dst = regB; rel = b - 4096; }
  else if (b < 9216) { src = wk; dst = regB + 4194304; rel = b - 8192; }
  else if (b < 10240) { src = wv; dst = regB + 5242880; rel = b - 9216; }
  else { src = wo; dst = regWo; rel = b - 10240; }
  const int i = (rel * 256 + threadIdx.x) * 4;
  float4 v = *(const float4*)(src + i);
  bf16x4_t o = {(bf16_t)v.x, (bf16_t)v.y, (bf16_t)v.z, (bf16_t)v.w};
  *(bf16x4_t*)(dst + i) = o;
}

// ---------------------------------------------------------------------------
// NT GEMM: C[M,N] = A[M,K] * B[N,K]^T, 64x128 tile, BK=64, 4 waves.
// LDS XOR swizzle: chunk (row r, 8-elem col-chunk q) lives at slot
// q ^ (r&7) within the row -> fragment reads are bank-conflict-free.
// Store side permutes the GLOBAL source address (global_load_lds dst is
// lane-contiguous and fixed); coalescing preserved within each 128B row.
// ROPE: rotary fused in epilogue (wave cols {0,16,64,80}+wn32 put (d,d+64)
// pairs in-lane) for output cols < 2560.
// ---------------------------------------------------------------------------
template <typename OutT, bool ROPE>
__global__ __launch_bounds__(256) void gemm_bt64(const bf16_t* __restrict__ A,
                                                 const bf16_t* __restrict__ B,
                                                 OutT* __restrict__ C,
                                                 int M, int N, int K) {
  __shared__ bf16_t As[64 * 64];
  __shared__ bf16_t Bs[128 * 64];
  const int tid = threadIdx.x;
  const int lane = tid & 63;
  const int quad = lane >> 4;
  const int l15 = lane & 15;
  const int l7 = l15 & 7;
  const int wave = tid >> 6;
  const int bm = blockIdx.x * 64;
  const int bn = blockIdx.y * 128;
  const int wm = (wave >> 1) * 32;
  const int wn32 = (wave & 1) * 32;
  const int coff[4] = {wn32, wn32 + 16, wn32 + 64, wn32 + 80};

  f32x4_t acc[2][4] = {};

  for (int k0 = 0; k0 < K; k0 += 64) {
#pragma unroll
    for (int it = 0; it < 2; ++it) {
      const int slot = it * 256 + tid;          // 16B chunk index
      const int r = slot >> 3;
      const int q = (slot & 7) ^ (r & 7);       // swizzled source chunk
      const int wbase = it * 2048 + (tid & 192) * 8;
      async_copy16(As + wbase, A + (size_t)(bm + r) * K + k0 + q * 8);
    }
#pragma unroll
    for (int it = 0; it < 4; ++it) {
      const int slot = it * 256 + tid;
      const int r = slot >> 3;
      const int q = (slot & 7) ^ (r & 7);
      const int wbase = it * 2048 + (tid & 192) * 8;
      async_copy16(Bs + wbase, B + (size_t)(bn + r) * K + k0 + q * 8);
    }
    __syncthreads();
#pragma unroll
    for (int kk = 0; kk < 64; kk += 32) {
      const int kc = kk >> 3;  // base chunk of this k-window
      bf16x8_t af[2], bfv[4];
#pragma unroll
      for (int i = 0; i < 2; ++i)
        af[i] = *(const bf16x8_t*)(As + (wm + i * 16 + l15) * 64 +
                                   (((kc + quad) ^ l7) * 8));
#pragma unroll
      for (int i = 0; i < 4; ++i)
        bfv[i] = *(const bf16x8_t*)(Bs + (coff[i] + l15) * 64 +
                                    (((kc + quad) ^ l7) * 8));
#pragma unroll
      for (int mi = 0; mi < 2; ++mi)
#pragma unroll
        for (int ni = 0; ni < 4; ++ni)
          acc[mi][ni] = __builtin_amdgcn_mfma_f32_16x16x32_bf16(
              af[mi], bfv[ni], acc[mi][ni], 0, 0, 0);
    }
    __syncthreads();
  }

  if (ROPE && bn < 2560) {  // q/k columns; v (>=2560) skips
#pragma unroll
    for (int pair = 0; pair < 2; ++pair) {
      const int i_d = wn32 + pair * 16 + l15;  // head-relative d in [0,64)
      const float inv = exp2f(-(float)i_d * 0.20762050593045702f);
#pragma unroll
      for (int mi = 0; mi < 2; ++mi) {
#pragma unroll
        for (int r = 0; r < 4; ++r) {
          const int s_row = bm + wm + mi * 16 + quad * 4 + r;
          float sn, cs;
          sincosf((float)s_row * inv, &sn, &cs);
          const float x0 = acc[mi][pair][r];
          const float x1 = acc[mi][pair + 2][r];
          acc[mi][pair][r] = x0 * cs - x1 * sn;
          acc[mi][pair + 2][r] = x1 * cs + x0 * sn;
        }
      }
    }
  }

  // C/D layout: col = lane&15, row = quad*4 + reg
#pragma unroll
  for (int mi = 0; mi < 2; ++mi) {
#pragma unroll
    for (int r = 0; r < 4; ++r) {
      const int row = bm + wm + mi * 16 + quad * 4 + r;
#pragma unroll
      for (int ni = 0; ni < 4; ++ni)
        C[(size_t)row * N + bn + coff[ni] + l15] = (OutT)acc[mi][ni][r];
    }
  }
}

// ---------------------------------------------------------------------------
// Flash attention, causal, GQA, split-KV x2 with additive fp32 partials.
// Block = (64 q-rows, 1 head, 1 kv-half); 1024 blocks, 4/CU co-resident;
// complementary mapping keeps each CU at ~33 kv-tiles.
// Fixed-max softmax (p = exp(s*scale-16)) makes O/l partials additive.
// All LDS tiles XOR-swizzled (no padding): 40 KB -> 4 blocks/CU.
// ---------------------------------------------------------------------------
__global__ __launch_bounds__(256, 4) void attn_kernel(
    const bf16_t* __restrict__ qkv, float* __restrict__ Op,
    float* __restrict__ lp) {
  __shared__ bf16_t Ks[64 * 128];    // [key][d], swizzle ^(key&15)
  __shared__ bf16_t Vt[128 * 64];    // [d][key], swizzle ^(d&7)
  __shared__ bf16_t Ps[4 * 16 * 64]; // per-wave, swizzle ^(row&7)
  const int tid = threadIdx.x;
  const int lane = tid & 63;
  const int wave = tid >> 6;
  const int quad = lane >> 4;
  const int l15 = lane & 15;
  const int l7 = l15 & 7;
  const int j = blockIdx.x;
  const int half = j >> 9;
  const int j2 = j & 511;
  const int qb = (j2 < 256) ? (31 - (j2 >> 4)) : ((j2 - 256) >> 4);
  const int h = j2 & 15;
  const int kvh = h >> 2;
  const int nh0 = (qb + 2) >> 1;            // tiles in half 0 (ceil)
  const int kbS = half ? nh0 : 0;
  const int kbE = half ? (qb + 1) : nh0;
  const float scale = 0.08838834764831845f;  // 1/sqrt(128)

  // staging coordinates (iteration-invariant)
  const int rk0 = tid >> 4;        // K row within 16-row group
  const int cq = tid & 15;         // K col chunk
  const int dv2 = lane * 2;        // V d-pair base

  // Q fragments (A-operand)
  bf16x8_t qf[4];
  {
    const bf16_t* qbase =
        qkv + (size_t)(qb * 64 + wave * 16 + l15) * 3072 + h * 128 + quad * 8;
#pragma unroll
    for (int kf = 0; kf < 4; ++kf) qf[kf] = *(const bf16x8_t*)(qbase + kf * 32);
  }

  f32x4_t o[8] = {};
  float lsum[4] = {0.f, 0.f, 0.f, 0.f};

  bf16x8_t kreg[4];
  uint32_t vbuf[2][8];
  auto load_tile = [&](int kb) {
    const bf16_t* kbase = qkv + (size_t)(kb * 64) * 3072 + 2048 + kvh * 128;
    const bf16_t* vbase = qkv + (size_t)(kb * 64) * 3072 + 2560 + kvh * 128;
#pragma unroll
    for (int it = 0; it < 4; ++it)
      kreg[it] = *(const bf16x8_t*)(kbase + (size_t)(it * 16 + rk0) * 3072 + cq * 8);
#pragma unroll
    for (int it = 0; it < 2; ++it) {
      const int kg8 = it * 4 + wave;  // key octet 0..7
#pragma unroll
      for (int t = 0; t < 8; ++t)
        vbuf[it][t] =
            *(const uint32_t*)(vbase + (size_t)(kg8 * 8 + t) * 3072 + dv2);
    }
  };

  if (kbS < kbE) {
    load_tile(kbS);

    for (int kb = kbS; kb < kbE; ++kb) {
      __syncthreads();  // prev iteration's Ks/Vt reads complete
#pragma unroll
      for (int it = 0; it < 4; ++it)
        *(bf16x8_t*)(Ks + (it * 16 + rk0) * 128 + ((cq ^ rk0) * 8)) = kreg[it];
#pragma unroll
      for (int it = 0; it < 2; ++it) {
        const int kg8 = it * 4 + wave;
        bf16x8_t lov, hiv;
#pragma unroll
        for (int t = 0; t < 8; ++t) {
          const uint32_t u = vbuf[it][t];
          lov[t] = __builtin_bit_cast(bf16_t, (unsigned short)(u & 0xffff));
          hiv[t] = __builtin_bit_cast(bf16_t, (unsigned short)(u >> 16));
        }
        *(bf16x8_t*)(Vt + (size_t)dv2 * 64 + ((kg8 ^ (dv2 & 7)) * 8)) = lov;
        *(bf16x8_t*)(Vt + (size_t)(dv2 + 1) * 64 + ((kg8 ^ ((dv2 + 1) & 7)) * 8)) = hiv;
      }
      __syncthreads();
      if (kb + 1 < kbE) load_tile(kb + 1);  // overlaps compute below

      // S = Q * K^T   (Ks swizzle: chunk = (kf*4+quad) ^ key&15, key&15 = l15)
      f32x4_t sc[4] = {};
#pragma unroll
      for (int kf = 0; kf < 4; ++kf) {
#pragma unroll
        for (int ni = 0; ni < 4; ++ni) {
          bf16x8_t bfr = *(const bf16x8_t*)(Ks + (ni * 16 + l15) * 128 +
                                            (((kf * 4 + quad) ^ l15) * 8));
          sc[ni] =
              __builtin_amdgcn_mfma_f32_16x16x32_bf16(qf[kf], bfr, sc[ni], 0, 0, 0);
        }
      }

      // fixed-max softmax: p = exp(s*scale - 16); causal mask -> -100 arg
      float p[4][4];
#pragma unroll
      for (int r = 0; r < 4; ++r) {
        const int sq = qb * 64 + wave * 16 + quad * 4 + r;
#pragma unroll
        for (int ni = 0; ni < 4; ++ni) {
          float arg = fmaf(sc[ni][r], scale, -16.0f);
          if (kb == qb && (kb * 64 + ni * 16 + l15) > sq) arg = -100.0f;
          const float e = __expf(arg);
          p[ni][r] = e;
          lsum[r] += e;
        }
      }

      // P: C layout -> LDS (wave-private, swizzled)
      bf16_t* pw = Ps + wave * 16 * 64;
#pragma unroll
      for (int ni = 0; ni < 4; ++ni)
#pragma unroll
        for (int r = 0; r < 4; ++r) {
          const int prow = quad * 4 + r;
          pw[prow * 64 + (((ni * 2 + (l15 >> 3)) ^ (prow & 7)) * 8) + l7] =
              (bf16_t)p[ni][r];
        }

      // O += P * V
#pragma unroll
      for (int kf = 0; kf < 2; ++kf) {
        bf16x8_t af = *(const bf16x8_t*)(pw + l15 * 64 +
                                         (((kf * 4 + quad) ^ l7) * 8));
#pragma unroll
        for (int ni = 0; ni < 8; ++ni) {
          bf16x8_t bfr = *(const bf16x8_t*)(Vt + (ni * 16 + l15) * 64 +
                                            (((kf * 4 + quad) ^ l7) * 8));
          o[ni] = __builtin_amdgcn_mfma_f32_16x16x32_bf16(af, bfr, o[ni], 0, 0, 0);
        }
      }
    }
  }

  // epilogue: reduce l across 16 lanes; store fp32 partials
#pragma unroll
  for (int m = 1; m <= 8; m <<= 1)
#pragma unroll
    for (int r = 0; r < 4; ++r) lsum[r] += __shfl_xor(lsum[r], m, 64);

  float* obase = Op + (size_t)half * 4194304 +
                 (size_t)(qb * 64 + wave * 16 + quad * 4) * 2048 + h * 128 + l15;
#pragma unroll
  for (int r = 0; r < 4; ++r) {
#pragma unroll
    for (int ni = 0; ni < 8; ++ni)
      obase[(size_t)r * 2048 + ni * 16] = o[ni][r];
    if (l15 == 0) {
      const int row = qb * 64 + wave * 16 + quad * 4 + r;
      lp[(half * 2048 + row) * 16 + h] = lsum[r];
    }
  }
}

// ---------------------------------------------------------------------------
// combine: out_bf16[s][col] = (O0 + O1) / (l0 + l1)
// ---------------------------------------------------------------------------
__global__ __launch_bounds__(256) void combine_kernel(
    const float* __restrict__ Op, const float* __restrict__ lp,
    bf16_t* __restrict__ out) {
  const int idx = (blockIdx.x * 256 + threadIdx.x) * 4;
  const int s = idx >> 11;
  const int col = idx & 2047;
  const int h = col >> 7;
  const float l = lp[s * 16 + h] + lp[(2048 + s) * 16 + h];
  const float inv = 1.0f / l;
  float4 a = *(const float4*)(Op + (size_t)s * 2048 + col);
  float4 b = *(const float4*)(Op + 4194304 + (size_t)s * 2048 + col);
  bf16x4_t o = {(bf16_t)((a.x + b.x) * inv), (bf16_t)((a.y + b.y) * inv),
                (bf16_t)((a.z + b.z) * inv), (bf16_t)((a.w + b.w) * inv)};
  *(bf16x4_t*)(out + idx) = o;
}

// ---------------------------------------------------------------------------
// ws layout (~61.3 MB, liveness-reused):
//   regA  [0,    8 MB)   hs_bf16          -> combine out (attn bf16)
//   regB  [8,   20.6 MB) Wqkv_bf16        (dead after QKV gemm)
//   Opart [8,   40 MB)   fp32 O partials  (overwrites regB)
//   regC  [40,  52.6 MB) qkv bf16 (RoPE applied in GEMM epilogue)
//   regWo [53,  61 MB)   Wo_bf16
//   lpart [61,  61.25)   fp32 l partials [2][2048][16]
// ---------------------------------------------------------------------------
extern "C" void kernel_launch(void* const* d_in, const int* in_sizes, int n_in,
                              void* d_out, int out_size, void* d_ws, size_t ws_size,
                              hipStream_t stream) {
  const float* hidden = (const float*)d_in[0];
  const float* Wq = (const float*)d_in[1];
  const float* Wk = (const float*)d_in[2];
  const float* Wv = (const float*)d_in[3];
  const float* Wo = (const float*)d_in[4];

  char* ws = (char*)d_ws;
  bf16_t* regA = (bf16_t*)ws;
  bf16_t* regB = (bf16_t*)(ws + (size_t)(8u << 20));
  float* Opart = (float*)(ws + (size_t)(8u << 20));
  bf16_t* regC = (bf16_t*)(ws + (size_t)(40u << 20));
  bf16_t* regWo = (bf16_t*)(ws + (size_t)(53u << 20));
  float* lpart = (float*)(ws + (size_t)(61u << 20));

  cvt_all<<<14336, 256, 0, stream>>>(hidden, Wq, Wk, Wv, Wo, regA, regB, regWo);

  // qkv = hidden @ [Wq;Wk;Wv]^T, RoPE fused -> regC [2048,3072]
  gemm_bt64<bf16_t, true><<<dim3(32, 24), 256, 0, stream>>>(regA, regB, regC,
                                                            2048, 3072, 2048);

  attn_kernel<<<1024, 256, 0, stream>>>(regC, Opart, lpart);

  combine_kernel<<<4096, 256, 0, stream>>>(Opart, lpart, regA);

  gemm_bt64<float, false><<<dim3(32, 16), 256, 0, stream>>>(
      regA, regWo, (float*)d_out, 2048, 2048, 2048);
}

// Round 8
// 217.366 us; speedup vs baseline: 1.2658x; 1.2658x over previous
//
#include <hip/hip_runtime.h>
#include <cstdint>
#include <cstddef>

// ---------------------------------------------------------------------------
// FlashSparseAttention on MI355X (gfx950)
// R8: swizzled GEMMs kept; attn = R6 body (reg prefetch, 2 barriers) +
//     XOR-swizzled LDS (40 KB exact) + split-KV x2 (1024 blocks, 4/CU,
//     complementary CU assignment) + plain launch_bounds (no VGPR coercion).
// ---------------------------------------------------------------------------

typedef __bf16 bf16_t;
typedef bf16_t bf16x4_t __attribute__((ext_vector_type(4)));
typedef bf16_t bf16x8_t __attribute__((ext_vector_type(8)));
typedef float f32x4_t __attribute__((ext_vector_type(4)));

__device__ __forceinline__ void async_copy16(void* lds_base, const void* gsrc) {
  auto g = reinterpret_cast<__attribute__((address_space(1))) void*>(
      reinterpret_cast<uintptr_t>(gsrc));
  auto l = reinterpret_cast<__attribute__((address_space(3))) void*>(
      static_cast<uint32_t>(reinterpret_cast<uintptr_t>(lds_base)));
  __builtin_amdgcn_global_load_lds(g, l, 16, 0, 0);
}

// ---------------------------------------------------------------------------
// fp32 -> bf16: merged conversion of hidden/Wq/Wk/Wv/Wo (one launch)
// ---------------------------------------------------------------------------
__global__ __launch_bounds__(256) void cvt_all(const float* __restrict__ hs,
                                               const float* __restrict__ wq,
                                               const float* __restrict__ wk,
                                               const float* __restrict__ wv,
                                               const float* __restrict__ wo,
                                               bf16_t* __restrict__ regA,
                                               bf16_t* __restrict__ regB,
                                               bf16_t* __restrict__ regWo) {
  const int b = blockIdx.x;
  const float* src;
  bf16_t* dst;
  int rel;
  if (b < 4096) { src = hs; dst = regA; rel = b; }
  else if (b < 8192) { src = wq; dst = regB; rel = b - 4096; }
  else if (b < 9216) { src = wk; dst = regB + 4194304; rel = b - 8192; }
  else if (b < 10240) { src = wv; dst = regB + 5242880; rel = b - 9216; }
  else { src = wo; dst = regWo; rel = b - 10240; }
  const int i = (rel * 256 + threadIdx.x) * 4;
  float4 v = *(const float4*)(src + i);
  bf16x4_t o = {(bf16_t)v.x, (bf16_t)v.y, (bf16_t)v.z, (bf16_t)v.w};
  *(bf16x4_t*)(dst + i) = o;
}

// ---------------------------------------------------------------------------
// NT GEMM: C[M,N] = A[M,K] * B[N,K]^T, 64x128 tile, BK=64, 4 waves.
// LDS XOR swizzle (chunk q of row r at slot q^(r&7)); store side permutes
// the GLOBAL source address, keeping global_load_lds + coalescing.
// ROPE fused in epilogue for output cols < 2560.
// ---------------------------------------------------------------------------
template <typename OutT, bool ROPE>
__global__ __launch_bounds__(256) void gemm_bt64(const bf16_t* __restrict__ A,
                                                 const bf16_t* __restrict__ B,
                                                 OutT* __restrict__ C,
                                                 int M, int N, int K) {
  __shared__ bf16_t As[64 * 64];
  __shared__ bf16_t Bs[128 * 64];
  const int tid = threadIdx.x;
  const int lane = tid & 63;
  const int quad = lane >> 4;
  const int l15 = lane & 15;
  const int l7 = l15 & 7;
  const int wave = tid >> 6;
  const int bm = blockIdx.x * 64;
  const int bn = blockIdx.y * 128;
  const int wm = (wave >> 1) * 32;
  const int wn32 = (wave & 1) * 32;
  const int coff[4] = {wn32, wn32 + 16, wn32 + 64, wn32 + 80};

  f32x4_t acc[2][4] = {};

  for (int k0 = 0; k0 < K; k0 += 64) {
#pragma unroll
    for (int it = 0; it < 2; ++it) {
      const int slot = it * 256 + tid;          // 16B chunk index
      const int r = slot >> 3;
      const int q = (slot & 7) ^ (r & 7);       // swizzled source chunk
      const int wbase = it * 2048 + (tid & 192) * 8;
      async_copy16(As + wbase, A + (size_t)(bm + r) * K + k0 + q * 8);
    }
#pragma unroll
    for (int it = 0; it < 4; ++it) {
      const int slot = it * 256 + tid;
      const int r = slot >> 3;
      const int q = (slot & 7) ^ (r & 7);
      const int wbase = it * 2048 + (tid & 192) * 8;
      async_copy16(Bs + wbase, B + (size_t)(bn + r) * K + k0 + q * 8);
    }
    __syncthreads();
#pragma unroll
    for (int kk = 0; kk < 64; kk += 32) {
      const int kc = kk >> 3;
      bf16x8_t af[2], bfv[4];
#pragma unroll
      for (int i = 0; i < 2; ++i)
        af[i] = *(const bf16x8_t*)(As + (wm + i * 16 + l15) * 64 +
                                   (((kc + quad) ^ l7) * 8));
#pragma unroll
      for (int i = 0; i < 4; ++i)
        bfv[i] = *(const bf16x8_t*)(Bs + (coff[i] + l15) * 64 +
                                    (((kc + quad) ^ l7) * 8));
#pragma unroll
      for (int mi = 0; mi < 2; ++mi)
#pragma unroll
        for (int ni = 0; ni < 4; ++ni)
          acc[mi][ni] = __builtin_amdgcn_mfma_f32_16x16x32_bf16(
              af[mi], bfv[ni], acc[mi][ni], 0, 0, 0);
    }
    __syncthreads();
  }

  if (ROPE && bn < 2560) {  // q/k columns; v (>=2560) skips
#pragma unroll
    for (int pair = 0; pair < 2; ++pair) {
      const int i_d = wn32 + pair * 16 + l15;  // head-relative d in [0,64)
      const float inv = exp2f(-(float)i_d * 0.20762050593045702f);
#pragma unroll
      for (int mi = 0; mi < 2; ++mi) {
#pragma unroll
        for (int r = 0; r < 4; ++r) {
          const int s_row = bm + wm + mi * 16 + quad * 4 + r;
          float sn, cs;
          sincosf((float)s_row * inv, &sn, &cs);
          const float x0 = acc[mi][pair][r];
          const float x1 = acc[mi][pair + 2][r];
          acc[mi][pair][r] = x0 * cs - x1 * sn;
          acc[mi][pair + 2][r] = x1 * cs + x0 * sn;
        }
      }
    }
  }

  // C/D layout: col = lane&15, row = quad*4 + reg
#pragma unroll
  for (int mi = 0; mi < 2; ++mi) {
#pragma unroll
    for (int r = 0; r < 4; ++r) {
      const int row = bm + wm + mi * 16 + quad * 4 + r;
#pragma unroll
      for (int ni = 0; ni < 4; ++ni)
        C[(size_t)row * N + bn + coff[ni] + l15] = (OutT)acc[mi][ni][r];
    }
  }
}

// ---------------------------------------------------------------------------
// Flash attention, causal, GQA, split-KV x2 (additive fp32 partials via
// fixed-max softmax).  1024 blocks; complementary mapping: the 4 blocks
// co-resident on a CU (j, j+256 over both halves) total exactly 33 kv-tiles.
// R6 body: register K/V prefetch during compute, 2 barriers/tile.
// XOR-swizzled LDS, no padding: exactly 40 KB -> 4 blocks/CU at ~120 VGPR.
// ---------------------------------------------------------------------------
__global__ __launch_bounds__(256) void attn_kernel(
    const bf16_t* __restrict__ qkv, float* __restrict__ Op,
    float* __restrict__ lp) {
  __shared__ bf16_t Ks[64 * 128];    // [key][d], chunk ^ (key&15)
  __shared__ bf16_t Vt[128 * 64];    // [d][key], chunk ^ (d&7)
  __shared__ bf16_t Ps[4 * 16 * 64]; // per-wave, chunk ^ (row&7)
  const int tid = threadIdx.x;
  const int lane = tid & 63;
  const int wave = tid >> 6;
  const int quad = lane >> 4;
  const int l15 = lane & 15;
  const int l7 = l15 & 7;
  const int j = blockIdx.x;
  const int half = j >> 9;
  const int j2 = j & 511;
  const int qb = (j2 < 256) ? (31 - (j2 >> 4)) : ((j2 - 256) >> 4);
  const int h = j2 & 15;
  const int kvh = h >> 2;
  const int nh0 = (qb + 2) >> 1;             // tiles in half 0
  const int kbS = half ? nh0 : 0;
  const int kbE = half ? (qb + 1) : nh0;
  const float scale = 0.08838834764831845f;  // 1/sqrt(128)

  // staging coordinates (iteration-invariant)
  const int rk0 = tid >> 4;        // K row within 16-row group
  const int cq = tid & 15;         // K col chunk
  const int dv2 = lane * 2;        // V d-pair base

  // Q fragments (A-operand)
  bf16x8_t qf[4];
  {
    const bf16_t* qbase =
        qkv + (size_t)(qb * 64 + wave * 16 + l15) * 3072 + h * 128 + quad * 8;
#pragma unroll
    for (int kf = 0; kf < 4; ++kf) qf[kf] = *(const bf16x8_t*)(qbase + kf * 32);
  }

  f32x4_t o[8] = {};
  float lsum[4] = {0.f, 0.f, 0.f, 0.f};

  bf16x8_t kreg[4];
  uint32_t vbuf[2][8];
  auto load_tile = [&](int kb) {
    const bf16_t* kbase = qkv + (size_t)(kb * 64) * 3072 + 2048 + kvh * 128;
    const bf16_t* vbase = qkv + (size_t)(kb * 64) * 3072 + 2560 + kvh * 128;
#pragma unroll
    for (int it = 0; it < 4; ++it)
      kreg[it] =
          *(const bf16x8_t*)(kbase + (size_t)(it * 16 + rk0) * 3072 + cq * 8);
#pragma unroll
    for (int it = 0; it < 2; ++it) {
      const int kg8 = it * 4 + wave;  // key octet 0..7
#pragma unroll
      for (int t = 0; t < 8; ++t)
        vbuf[it][t] =
            *(const uint32_t*)(vbase + (size_t)(kg8 * 8 + t) * 3072 + dv2);
    }
  };

  if (kbS < kbE) {
    load_tile(kbS);

    for (int kb = kbS; kb < kbE; ++kb) {
      __syncthreads();  // prev iteration's Ks/Vt reads complete
#pragma unroll
      for (int it = 0; it < 4; ++it)
        *(bf16x8_t*)(Ks + (it * 16 + rk0) * 128 + ((cq ^ rk0) * 8)) = kreg[it];
#pragma unroll
      for (int it = 0; it < 2; ++it) {
        const int kg8 = it * 4 + wave;
        bf16x8_t lov, hiv;
#pragma unroll
        for (int t = 0; t < 8; ++t) {
          const uint32_t u = vbuf[it][t];
          lov[t] = __builtin_bit_cast(bf16_t, (unsigned short)(u & 0xffff));
          hiv[t] = __builtin_bit_cast(bf16_t, (unsigned short)(u >> 16));
        }
        *(bf16x8_t*)(Vt + (size_t)dv2 * 64 + ((kg8 ^ (dv2 & 7)) * 8)) = lov;
        *(bf16x8_t*)(Vt + (size_t)(dv2 + 1) * 64 +
                     ((kg8 ^ ((dv2 + 1) & 7)) * 8)) = hiv;
      }
      __syncthreads();
      if (kb + 1 < kbE) load_tile(kb + 1);  // overlaps compute below

      // S = Q * K^T
      f32x4_t sc[4] = {};
#pragma unroll
      for (int kf = 0; kf < 4; ++kf) {
#pragma unroll
        for (int ni = 0; ni < 4; ++ni) {
          bf16x8_t bfr = *(const bf16x8_t*)(Ks + (ni * 16 + l15) * 128 +
                                            (((kf * 4 + quad) ^ l15) * 8));
          sc[ni] = __builtin_amdgcn_mfma_f32_16x16x32_bf16(qf[kf], bfr, sc[ni],
                                                           0, 0, 0);
        }
      }

      // fixed-max softmax: p = exp(s*scale - 16); causal mask -> -100 arg
      float p[4][4];
#pragma unroll
      for (int r = 0; r < 4; ++r) {
        const int sq = qb * 64 + wave * 16 + quad * 4 + r;
#pragma unroll
        for (int ni = 0; ni < 4; ++ni) {
          float arg = fmaf(sc[ni][r], scale, -16.0f);
          if (kb == qb && (kb * 64 + ni * 16 + l15) > sq) arg = -100.0f;
          const float e = __expf(arg);
          p[ni][r] = e;
          lsum[r] += e;
        }
      }

      // P: C layout -> LDS (wave-private, swizzled)
      bf16_t* pw = Ps + wave * 16 * 64;
#pragma unroll
      for (int ni = 0; ni < 4; ++ni)
#pragma unroll
        for (int r = 0; r < 4; ++r) {
          const int prow = quad * 4 + r;
          pw[prow * 64 + (((ni * 2 + (l15 >> 3)) ^ (prow & 7)) * 8) + l7] =
              (bf16_t)p[ni][r];
        }

      // O += P * V
#pragma unroll
      for (int kf = 0; kf < 2; ++kf) {
        bf16x8_t af =
            *(const bf16x8_t*)(pw + l15 * 64 + (((kf * 4 + quad) ^ l7) * 8));
#pragma unroll
        for (int ni = 0; ni < 8; ++ni) {
          bf16x8_t bfr = *(const bf16x8_t*)(Vt + (ni * 16 + l15) * 64 +
                                            (((kf * 4 + quad) ^ l7) * 8));
          o[ni] =
              __builtin_amdgcn_mfma_f32_16x16x32_bf16(af, bfr, o[ni], 0, 0, 0);
        }
      }
    }
  }

  // epilogue: reduce l across 16 lanes; store fp32 partials
#pragma unroll
  for (int m = 1; m <= 8; m <<= 1)
#pragma unroll
    for (int r = 0; r < 4; ++r) lsum[r] += __shfl_xor(lsum[r], m, 64);

  float* obase = Op + (size_t)half * 4194304 +
                 (size_t)(qb * 64 + wave * 16 + quad * 4) * 2048 + h * 128 + l15;
#pragma unroll
  for (int r = 0; r < 4; ++r) {
#pragma unroll
    for (int ni = 0; ni < 8; ++ni)
      obase[(size_t)r * 2048 + ni * 16] = o[ni][r];
    if (l15 == 0) {
      const int row = qb * 64 + wave * 16 + quad * 4 + r;
      lp[(half * 2048 + row) * 16 + h] = lsum[r];
    }
  }
}

// ---------------------------------------------------------------------------
// combine: out_bf16[s][col] = (O0 + O1) / (l0 + l1)
// ---------------------------------------------------------------------------
__global__ __launch_bounds__(256) void combine_kernel(
    const float* __restrict__ Op, const float* __restrict__ lp,
    bf16_t* __restrict__ out) {
  const int idx = (blockIdx.x * 256 + threadIdx.x) * 4;
  const int s = idx >> 11;
  const int col = idx & 2047;
  const int h = col >> 7;
  const float l = lp[s * 16 + h] + lp[(2048 + s) * 16 + h];
  const float inv = 1.0f / l;
  float4 a = *(const float4*)(Op + (size_t)s * 2048 + col);
  float4 b = *(const float4*)(Op + 4194304 + (size_t)s * 2048 + col);
  bf16x4_t o = {(bf16_t)((a.x + b.x) * inv), (bf16_t)((a.y + b.y) * inv),
                (bf16_t)((a.z + b.z) * inv), (bf16_t)((a.w + b.w) * inv)};
  *(bf16x4_t*)(out + idx) = o;
}

// ---------------------------------------------------------------------------
// ws layout (~61.3 MB, liveness-reused):
//   regA  [0,    8 MB)   hs_bf16          -> combine out (attn bf16)
//   regB  [8,   20.6 MB) Wqkv_bf16        (dead after QKV gemm)
//   Opart [8,   40 MB)   fp32 O partials  (overwrites regB)
//   regC  [40,  52.6 MB) qkv bf16 (RoPE applied in GEMM epilogue)
//   regWo [53,  61 MB)   Wo_bf16
//   lpart [61,  61.25)   fp32 l partials [2][2048][16]
// ---------------------------------------------------------------------------
extern "C" void kernel_launch(void* const* d_in, const int* in_sizes, int n_in,
                              void* d_out, int out_size, void* d_ws, size_t ws_size,
                              hipStream_t stream) {
  const float* hidden = (const float*)d_in[0];
  const float* Wq = (const float*)d_in[1];
  const float* Wk = (const float*)d_in[2];
  const float* Wv = (const float*)d_in[3];
  const float* Wo = (const float*)d_in[4];

  char* ws = (char*)d_ws;
  bf16_t* regA = (bf16_t*)ws;
  bf16_t* regB = (bf16_t*)(ws + (size_t)(8u << 20));
  float* Opart = (float*)(ws + (size_t)(8u << 20));
  bf16_t* regC = (bf16_t*)(ws + (size_t)(40u << 20));
  bf16_t* regWo = (bf16_t*)(ws + (size_t)(53u << 20));
  float* lpart = (float*)(ws + (size_t)(61u << 20));

  cvt_all<<<14336, 256, 0, stream>>>(hidden, Wq, Wk, Wv, Wo, regA, regB, regWo);

  // qkv = hidden @ [Wq;Wk;Wv]^T, RoPE fused -> regC [2048,3072]
  gemm_bt64<bf16_t, true><<<dim3(32, 24), 256, 0, stream>>>(regA, regB, regC,
                                                            2048, 3072, 2048);

  attn_kernel<<<1024, 256, 0, stream>>>(regC, Opart, lpart);

  combine_kernel<<<4096, 256, 0, stream>>>(Opart, lpart, regA);

  gemm_bt64<float, false><<<dim3(32, 16), 256, 0, stream>>>(
      regA, regWo, (float*)d_out, 2048, 2048, 2048);
}